// Round 3
// baseline (78680.127 us; speedup 1.0000x reference)
//
#include <hip/hip_runtime.h>
#include <cstdint>
#include <cstddef>

#define SEQ       32768
#define NT        512
#define START_TAG 510
#define END_TAG   511
#define NEGF      -10000.0f
#define KCH       64
#define NCH       (SEQ / KCH)   /* 512 chunks */

#define NBLK      16            /* forward blocks */
#define TPB       576           /* 9 waves: wave 0 polls, waves 1..8 compute */
#define CPB       32            /* columns owned per block (NT/NBLK) */

/* workspace layout (64B aligned)
   bp  : 32 MiB  backpointers (u16)
   M   : 512 KiB chunk-composed maps
   bd  : 2 KiB   chunk boundary tags
   AgP : 8 KiB   packed (tag<<32 | alpha_bits) ping-pong slots            */
#define BP_BYTES  ((size_t)SEQ * NT * sizeof(unsigned short))
#define M_OFF     (BP_BYTES)
#define M_BYTES   ((size_t)NCH * NT * sizeof(unsigned short))
#define BD_OFF    (M_OFF + M_BYTES)
#define BD_BYTES  ((size_t)NCH * sizeof(int))
#define AG_OFF    ((BD_OFF + BD_BYTES + 63) & ~(size_t)63)

/* ---------- kernel 0: init packed alpha slots ----------
   buffer0 = (tag 0, alpha_0); buffer1 = (tag 0xFFFFFFFF, junk) -> never matches */
__global__ __launch_bounds__(NT) void init_k(unsigned long long* AgP) {
    const int t = threadIdx.x;
    const float a0 = (t == START_TAG) ? 0.0f : NEGF;
    AgP[t]      = (unsigned long long)__float_as_uint(a0);
    AgP[NT + t] = ((unsigned long long)0xFFFFFFFFu << 32)
                | (unsigned long long)__float_as_uint(NEGF);
}

/* ---------- kernel 1: poller/compute wave-specialized Viterbi forward ----------
   16 blocks x 9 waves. Block b owns columns [32b, 32b+32).
   WAVE 0 = dedicated poller: spins on the 512 tagged slots for step t,
   scatters them (XOR-swizzled) into LDS parity buffer, hits the barrier,
   then IMMEDIATELY starts polling step t+1 while waves 1..8 compute step t.
   The poll round trip thus overlaps the compute+publish phase.
   WAVES 1..8 = compute: wave cwv owns 4 columns; lane = g*16+m (g=column,
   m=i-chunk lane), lane scans i in [32m,32m+32) with 32 trans values in
   registers; 16-lane shfl_xor butterfly argmax; column leaders publish
   tagged slots (4 consecutive 8B stores per wave coalesce to 32B).
   Safety: tag==t IS validity (value data-depends on the polled word, no
   fences); parity ping-pong + the transitive barrier chain give a provable
   >=2-step overwrite lag, cross-block and in-LDS alike.                   */
__global__ __launch_bounds__(TPB) void viterbi_fwd(const float* __restrict__ u,
                                                   const float* __restrict__ trans,
                                                   unsigned short* __restrict__ bp,
                                                   unsigned long long* AgP) {
    __shared__ float4 abuf[2][NT / 4];       /* parity ping-pong, 2 KiB each */

    const int tid  = threadIdx.x;
    const int wv   = tid >> 6;               /* 0 = poller, 1..8 compute */
    const int lane = tid & 63;
    const int b    = (int)blockIdx.x;

    if (wv == 0) {
        /* ---------------- dedicated poller wave ---------------- */
        for (int t = 0; t < SEQ; ++t) {
            const int par = t & 1;
            const unsigned long long* sb = AgP + (size_t)par * NT + lane;
            unsigned long long va[8];
            const unsigned expt = (unsigned)t;
            for (;;) {                       /* no sleep: spin is vmcnt-blocked */
                bool ok = true;
                #pragma unroll
                for (int r = 0; r < 8; ++r) {
                    va[r] = __hip_atomic_load(&sb[r * 64], __ATOMIC_RELAXED,
                                              __HIP_MEMORY_SCOPE_AGENT);
                    ok &= ((unsigned)(va[r] >> 32) == expt);
                }
                if (ok) break;
            }
            /* scatter, XOR-swizzled: phys(i) = i ^ (((i>>5)&7)<<2)
               (conflict-free: per half-wave a pure bank permutation)     */
            float* awf = (float*)&abuf[par][0];
            #pragma unroll
            for (int r = 0; r < 8; ++r) {
                const int i    = r * 64 + lane;
                const int phys = i ^ (((i >> 5) & 7) << 2);
                awf[phys] = __uint_as_float((unsigned)va[r]);
            }
            __syncthreads();                 /* releases compute waves for t */
        }
    } else {
        /* ---------------- compute waves ---------------- */
        const int cwv = wv - 1;              /* 0..7 */
        const int g   = lane >> 4;           /* column within wave 0..3 */
        const int m   = lane & 15;           /* i-chunk lane 0..15 */
        const int j   = b * CPB + cwv * 4 + g;
        const int i0  = 32 * m;              /* candidate base, 32 per lane */

        /* stage 32 transition values: trans[j][i0..i0+32) as 8 float4 */
        float4 treg[8];
        #pragma unroll
        for (int q = 0; q < 8; ++q)
            treg[q] = *(const float4*)&trans[(size_t)j * NT + i0 + 4 * q];

        float uval = 0.0f;
        if (m == 0) uval = u[j];

        for (int t = 0; t < SEQ; ++t) {
            const int par = t & 1;

            /* prefetch next u before the barrier: overlaps wait + compute */
            float unext = 0.0f;
            const int tn = (t + 1 < SEQ) ? (t + 1) : t;
            if (m == 0) unext = u[(size_t)tn * NT + j];

            __syncthreads();                 /* wait for poller's scatter of t */

            /* 8 independent 4-candidate chains (dep depth 4), tree-merged.
               Ascending i everywhere + strict '>' / keep-left => lowest index
               wins ties (jnp.argmax semantics).                             */
            float bv8[8]; int bi8[8];
            #pragma unroll
            for (int q = 0; q < 8; ++q) {
                const int ib  = i0 + 4 * q;
                const int f4i = ((ib >> 2) ^ (m & 7));   /* swizzled float4 idx */
                const float4 a4 = abuf[par][f4i];
                const float4 tq = treg[q];
                float bv = a4.x + tq.x; int bi = ib;
                float s;
                s = a4.y + tq.y; if (s > bv) { bv = s; bi = ib + 1; }
                s = a4.z + tq.z; if (s > bv) { bv = s; bi = ib + 2; }
                s = a4.w + tq.w; if (s > bv) { bv = s; bi = ib + 3; }
                bv8[q] = bv; bi8[q] = bi;
            }
            #pragma unroll
            for (int st = 1; st < 8; st <<= 1)
                #pragma unroll
                for (int q = 0; q < 8; q += 2 * st)
                    if (bv8[q + st] > bv8[q]) { bv8[q] = bv8[q + st]; bi8[q] = bi8[q + st]; }
            float bv = bv8[0]; int bi = bi8[0];

            /* 16-lane butterfly argmax (tie: lowest i wins) */
            #pragma unroll
            for (int h = 1; h <= 8; h <<= 1) {
                const float ov = __shfl_xor(bv, h);
                const int   oi = __shfl_xor(bi, h);
                if (ov > bv || (ov == bv && oi < bi)) { bv = ov; bi = oi; }
            }

            /* publish FIRST (starts the agent-store drain ASAP) */
            if (m == 0) {
                const float na = bv + uval;
                const unsigned long long pk =
                    ((unsigned long long)(unsigned)(t + 1) << 32)
                    | (unsigned long long)__float_as_uint(na);
                __hip_atomic_store(&AgP[(size_t)((t + 1) & 1) * NT + j], pk,
                                   __ATOMIC_RELAXED, __HIP_MEMORY_SCOPE_AGENT);
            }

            /* backpointers: gather the wave's 4 column results, one 8B store */
            const int r1 = __shfl(bi, 16);
            const int r2 = __shfl(bi, 32);
            const int r3 = __shfl(bi, 48);
            if (lane == 0) {
                uint2 pk2;
                pk2.x = (unsigned)(bi & 0xFFFF) | ((unsigned)r1 << 16);
                pk2.y = (unsigned)(r2 & 0xFFFF) | ((unsigned)r3 << 16);
                *(uint2*)&bp[(size_t)t * NT + b * CPB + cwv * 4] = pk2;
            }
            uval = unext;
        }
    }
}

/* ---------- kernel 2: parallel chunk-map composition from bp ---------- */
__global__ __launch_bounds__(NT) void mbuild_k(const unsigned short* __restrict__ bp,
                                               unsigned short* __restrict__ M) {
    __shared__ unsigned short R[2][NT];
    const int c = (int)blockIdx.x, j = threadIdx.x;
    const size_t base = (size_t)c * KCH * NT;
    R[0][j] = bp[base + j];
    int cb = 0;
    for (int t = 1; t < KCH; ++t) {
        const unsigned short r = bp[base + (size_t)t * NT + j];
        __syncthreads();
        R[cb ^ 1][j] = R[cb][r];
        cb ^= 1;
    }
    __syncthreads();
    M[(size_t)c * NT + j] = R[cb][j];
}

/* ---------- kernel 3: terminal argmax + chunk-boundary chase ---------- */
__global__ __launch_bounds__(NT) void chase_k(const unsigned long long* __restrict__ AgP,
                                              const float* __restrict__ tr,
                                              const unsigned short* __restrict__ M,
                                              int* __restrict__ boundary,
                                              float* __restrict__ out) {
    __shared__ float sv[NT];
    __shared__ int   si[NT];
    const int j = threadIdx.x;
    /* alpha_SEQ lives in buffer 0 (SEQ even); low 32 bits = float value */
    sv[j] = __uint_as_float((unsigned)AgP[j]) + tr[(size_t)END_TAG * NT + j];
    si[j] = j;
    __syncthreads();
    for (int off = NT / 2; off > 0; off >>= 1) {
        if (j < off) {
            const float a = sv[j], b = sv[j + off];
            if (b > a || (b == a && si[j + off] < si[j])) { sv[j] = b; si[j] = si[j + off]; }
        }
        __syncthreads();
    }
    if (j == 0) {
        out[SEQ] = sv[0];                 /* path_score */
        int tag = si[0];                  /* path[32767] */
        boundary[NCH - 1] = tag;
        for (int c = NCH - 1; c >= 1; --c) {
            tag = (int)M[(size_t)c * NT + tag];
            boundary[c - 1] = tag;
        }
    }
}

/* ---------- kernel 4: 512 independent per-chunk local tracebacks ---------- */
__global__ __launch_bounds__(64) void traceback_k(const unsigned short* __restrict__ bp,
                                                  const int* __restrict__ boundary,
                                                  float* __restrict__ out) {
    if (threadIdx.x != 0) return;
    const int c    = (int)blockIdx.x;
    int       tag  = boundary[c];            /* = path[(c+1)K - 1] */
    const int tend = (c + 1) * KCH - 1;
    out[tend] = (float)tag;
    for (int t = tend - 1; t >= c * KCH; --t) {
        tag = (int)bp[(size_t)(t + 1) * NT + tag];
        out[t] = (float)tag;
    }
}

extern "C" void kernel_launch(void* const* d_in, const int* in_sizes, int n_in,
                              void* d_out, int out_size, void* d_ws, size_t ws_size,
                              hipStream_t stream) {
    const float* unary = (const float*)d_in[0];   /* (32768,1,512) f32 */
    const float* trans = (const float*)d_in[1];   /* (1,512,512)   f32 */
    float* out = (float*)d_out;                   /* [0..32767]=path, [32768]=score */
    char*  ws  = (char*)d_ws;

    unsigned short*     bp       = (unsigned short*)ws;
    unsigned short*     M        = (unsigned short*)(ws + M_OFF);
    int*                boundary = (int*)(ws + BD_OFF);
    unsigned long long* AgP      = (unsigned long long*)(ws + AG_OFF);
    (void)in_sizes; (void)n_in; (void)out_size; (void)ws_size;

    init_k<<<1, NT, 0, stream>>>(AgP);
    viterbi_fwd<<<NBLK, TPB, 0, stream>>>(unary, trans, bp, AgP);
    mbuild_k<<<NCH, NT, 0, stream>>>(bp, M);
    chase_k<<<1, NT, 0, stream>>>(AgP, trans, M, boundary, out);
    traceback_k<<<NCH, 64, 0, stream>>>(bp, boundary, out);
}

// Round 5
// 69358.417 us; speedup vs baseline: 1.1344x; 1.1344x over previous
//
#include <hip/hip_runtime.h>
#include <cstdint>
#include <cstddef>

#define SEQ       32768
#define NT        512
#define START_TAG 510
#define END_TAG   511
#define NEGF      -10000.0f
#define KCH       64
#define NCH       (SEQ / KCH)   /* 512 chunks */

#define NBLK      16            /* forward blocks (= pollers = straggler set) */
#define TPB       1024          /* 16 waves per block */
#define CPB       32            /* columns owned per block (NT/NBLK) */

/* workspace layout (64B aligned)
   bp  : 32 MiB  backpointers (u16)
   M   : 512 KiB chunk-composed maps
   bd  : 2 KiB   chunk boundary tags
   AgP : 8 KiB   packed (tag<<32 | alpha_bits) ping-pong slots            */
#define BP_BYTES  ((size_t)SEQ * NT * sizeof(unsigned short))
#define M_OFF     (BP_BYTES)
#define M_BYTES   ((size_t)NCH * NT * sizeof(unsigned short))
#define BD_OFF    (M_OFF + M_BYTES)
#define BD_BYTES  ((size_t)NCH * sizeof(int))
#define AG_OFF    ((BD_OFF + BD_BYTES + 63) & ~(size_t)63)

/* ---------- kernel 0: init packed alpha slots ----------
   buffer0 = (tag 0, alpha_0); buffer1 = (tag ~0, junk) -> never matches */
__global__ __launch_bounds__(NT) void init_k(unsigned long long* AgP) {
    const int t = threadIdx.x;
    const float a0 = (t == START_TAG) ? 0.0f : NEGF;
    AgP[t]      = (unsigned long long)__float_as_uint(a0);
    AgP[NT + t] = ((unsigned long long)0xFFFFFFFFu << 32)
                | (unsigned long long)__float_as_uint(NEGF);
}

/* ---------- kernel 1: relay-polled wave-owned Viterbi forward ----------
   16 blocks x 16 waves. Block b owns columns [32b, 32b+32); wave wv covers
   columns {32b+2wv, +1}. Lane = gp*32 + m (gp = column within wave, m =
   i-chunk lane); lane scans i in [16m, 16m+16) with 16 transition values
   in registers (R2-proven compute shape, unchanged).
   Alpha exchange: one 64-bit slot per tag = (step<<32)|bits(alpha), relaxed
   agent scope. ONLY WAVE 0 of each block polls (16 pollers, no sleep); it
   scatters to parity-ping-ponged LDS and one __syncthreads releases the
   block. Tag-in-slot = validity (value data-depends on the polled word, so
   no fences); parity ping-pong + monotone tag + the transitive barrier
   chain give a provable >=2-step overwrite lag.                           */
__global__ __launch_bounds__(TPB) void viterbi_fwd(const float* __restrict__ u,
                                                   const float* __restrict__ trans,
                                                   unsigned short* __restrict__ bp,
                                                   unsigned long long* AgP) {
    __shared__ float4 abuf[2][NT / 4];       /* parity ping-pong, 2 KiB each */

    const int tid  = threadIdx.x;
    const int wv   = tid >> 6;               /* wave in block, 0..15 */
    const int lane = tid & 63;
    const int gp   = lane >> 5;              /* column within wave 0..1 */
    const int m    = lane & 31;              /* i-chunk lane 0..31 */
    const int b    = (int)blockIdx.x;
    const int jb   = b * CPB + wv * 2;       /* wave's column pair base */
    const int j    = jb + gp;                /* owned output column */
    const int i0   = 16 * m;                 /* this lane's candidate base */

    /* stage this lane's 16 transition values: trans[j][i0..i0+16) */
    const float4 t0 = *(const float4*)&trans[(size_t)j * NT + i0];
    const float4 t1 = *(const float4*)&trans[(size_t)j * NT + i0 + 4];
    const float4 t2 = *(const float4*)&trans[(size_t)j * NT + i0 + 8];
    const float4 t3 = *(const float4*)&trans[(size_t)j * NT + i0 + 12];

    /* u prefetch for t=0 (column leaders only) */
    float uval = 0.0f;
    if (m == 0) uval = u[j];

    for (int t = 0; t < SEQ; ++t) {
        const int par = t & 1;

        /* prefetch next step's u before the barrier (overlaps wait) */
        float unext = 0.0f;
        const int tn = (t + 1 < SEQ) ? (t + 1) : t;
        if (m == 0) unext = u[(size_t)tn * NT + j];

        if (wv == 0) {
            /* single poller wave: 8 interleaved tagged slots/lane (4 KiB);
               no sleep -- 16 pollers are far below MALL contention levels */
            const unsigned long long* sb = AgP + (size_t)par * NT + lane;
            unsigned long long va[8];
            const unsigned expt = (unsigned)t;
            for (;;) {
                bool ok = true;
                #pragma unroll
                for (int r = 0; r < 8; ++r) {
                    va[r] = __hip_atomic_load(&sb[r * 64], __ATOMIC_RELAXED,
                                              __HIP_MEMORY_SCOPE_AGENT);
                    ok &= ((unsigned)(va[r] >> 32) == expt);
                }
                if (ok) break;
            }
            /* scatter to LDS, XOR-swizzled: phys(i) = i ^ (((i>>5)&7)<<2) */
            float* awf = (float*)&abuf[par][0];
            #pragma unroll
            for (int r = 0; r < 8; ++r) {
                const int i    = r * 64 + lane;
                const int phys = i ^ (((i >> 5) & 7) << 2);
                awf[phys] = __uint_as_float((unsigned)va[r]);
            }
        }
        __syncthreads();                     /* alpha_t visible block-wide */

        /* 4 independent 4-candidate chains (dep depth 4), merged; ascending
           i + strict '>' / keep-left => lowest index wins ties            */
        float v0, v1, v2, v3; int x0, x1, x2, x3; float s;
        {   const int ib = i0;      const int pb = ib ^ (((ib >> 5) & 7) << 2);
            const float4 a = abuf[par][pb >> 2];
            v0 = a.x + t0.x; x0 = ib;
            s = a.y + t0.y; if (s > v0) { v0 = s; x0 = ib + 1; }
            s = a.z + t0.z; if (s > v0) { v0 = s; x0 = ib + 2; }
            s = a.w + t0.w; if (s > v0) { v0 = s; x0 = ib + 3; } }
        {   const int ib = i0 + 4;  const int pb = ib ^ (((ib >> 5) & 7) << 2);
            const float4 a = abuf[par][pb >> 2];
            v1 = a.x + t1.x; x1 = ib;
            s = a.y + t1.y; if (s > v1) { v1 = s; x1 = ib + 1; }
            s = a.z + t1.z; if (s > v1) { v1 = s; x1 = ib + 2; }
            s = a.w + t1.w; if (s > v1) { v1 = s; x1 = ib + 3; } }
        {   const int ib = i0 + 8;  const int pb = ib ^ (((ib >> 5) & 7) << 2);
            const float4 a = abuf[par][pb >> 2];
            v2 = a.x + t2.x; x2 = ib;
            s = a.y + t2.y; if (s > v2) { v2 = s; x2 = ib + 1; }
            s = a.z + t2.z; if (s > v2) { v2 = s; x2 = ib + 2; }
            s = a.w + t2.w; if (s > v2) { v2 = s; x2 = ib + 3; } }
        {   const int ib = i0 + 12; const int pb = ib ^ (((ib >> 5) & 7) << 2);
            const float4 a = abuf[par][pb >> 2];
            v3 = a.x + t3.x; x3 = ib;
            s = a.y + t3.y; if (s > v3) { v3 = s; x3 = ib + 1; }
            s = a.z + t3.z; if (s > v3) { v3 = s; x3 = ib + 2; }
            s = a.w + t3.w; if (s > v3) { v3 = s; x3 = ib + 3; } }
        if (v1 > v0) { v0 = v1; x0 = x1; }   /* keep-left on ties */
        if (v3 > v2) { v2 = v3; x2 = x3; }
        if (v2 > v0) { v0 = v2; x0 = x2; }
        float bv = v0; int bi = x0;

        /* 32-lane butterfly argmax (tie: lowest i wins) */
        #pragma unroll
        for (int h = 1; h <= 16; h <<= 1) {
            const float ov = __shfl_xor(bv, h);
            const int   oi = __shfl_xor(bi, h);
            if (ov > bv || (ov == bv && oi < bi)) { bv = ov; bi = oi; }
        }

        /* publish FIRST: start the agent-store drain as early as possible */
        if (m == 0) {
            const float na = bv + uval;
            const unsigned long long pk =
                ((unsigned long long)(unsigned)(t + 1) << 32)
                | (unsigned long long)__float_as_uint(na);
            __hip_atomic_store(&AgP[(size_t)((t + 1) & 1) * NT + j], pk,
                               __ATOMIC_RELAXED, __HIP_MEMORY_SCOPE_AGENT);
        }

        /* backpointers: lane 0 packs the wave's two columns into one dword */
        const int oi1 = __shfl(bi, 32);      /* gp=1 result */
        if (lane == 0) {
            *(unsigned*)&bp[(size_t)t * NT + jb] =
                (unsigned)(bi & 0xFFFF) | ((unsigned)oi1 << 16);
        }
        uval = unext;
    }
}

/* ---------- kernel 2: parallel chunk-map composition from bp ---------- */
__global__ __launch_bounds__(NT) void mbuild_k(const unsigned short* __restrict__ bp,
                                               unsigned short* __restrict__ M) {
    __shared__ unsigned short R[2][NT];
    const int c = (int)blockIdx.x, j = threadIdx.x;
    const size_t base = (size_t)c * KCH * NT;
    R[0][j] = bp[base + j];
    int cb = 0;
    for (int t = 1; t < KCH; ++t) {
        const unsigned short r = bp[base + (size_t)t * NT + j];
        __syncthreads();
        R[cb ^ 1][j] = R[cb][r];
        cb ^= 1;
    }
    __syncthreads();
    M[(size_t)c * NT + j] = R[cb][j];
}

/* ---------- kernel 3: terminal argmax + chunk-boundary chase ---------- */
__global__ __launch_bounds__(NT) void chase_k(const unsigned long long* __restrict__ AgP,
                                              const float* __restrict__ tr,
                                              const unsigned short* __restrict__ M,
                                              int* __restrict__ boundary,
                                              float* __restrict__ out) {
    __shared__ float sv[NT];
    __shared__ int   si[NT];
    const int j = threadIdx.x;
    /* alpha_SEQ lives in buffer 0 (SEQ even); low 32 bits = float value */
    sv[j] = __uint_as_float((unsigned)AgP[j]) + tr[(size_t)END_TAG * NT + j];
    si[j] = j;
    __syncthreads();
    for (int off = NT / 2; off > 0; off >>= 1) {
        if (j < off) {
            const float a = sv[j], b = sv[j + off];
            if (b > a || (b == a && si[j + off] < si[j])) { sv[j] = b; si[j] = si[j + off]; }
        }
        __syncthreads();
    }
    if (j == 0) {
        out[SEQ] = sv[0];                 /* path_score */
        int tag = si[0];                  /* path[32767] */
        boundary[NCH - 1] = tag;
        for (int c = NCH - 1; c >= 1; --c) {
            tag = (int)M[(size_t)c * NT + tag];
            boundary[c - 1] = tag;
        }
    }
}

/* ---------- kernel 4: 512 independent per-chunk local tracebacks ---------- */
__global__ __launch_bounds__(64) void traceback_k(const unsigned short* __restrict__ bp,
                                                  const int* __restrict__ boundary,
                                                  float* __restrict__ out) {
    if (threadIdx.x != 0) return;
    const int c    = (int)blockIdx.x;
    int       tag  = boundary[c];            /* = path[(c+1)K - 1] */
    const int tend = (c + 1) * KCH - 1;
    out[tend] = (float)tag;
    for (int t = tend - 1; t >= c * KCH; --t) {
        tag = (int)bp[(size_t)(t + 1) * NT + tag];
        out[t] = (float)tag;
    }
}

extern "C" void kernel_launch(void* const* d_in, const int* in_sizes, int n_in,
                              void* d_out, int out_size, void* d_ws, size_t ws_size,
                              hipStream_t stream) {
    const float* unary = (const float*)d_in[0];   /* (32768,1,512) f32 */
    const float* trans = (const float*)d_in[1];   /* (1,512,512)   f32 */
    float* out = (float*)d_out;                   /* [0..32767]=path, [32768]=score */
    char*  ws  = (char*)d_ws;

    unsigned short*     bp       = (unsigned short*)ws;
    unsigned short*     M        = (unsigned short*)(ws + M_OFF);
    int*                boundary = (int*)(ws + BD_OFF);
    unsigned long long* AgP      = (unsigned long long*)(ws + AG_OFF);
    (void)in_sizes; (void)n_in; (void)out_size; (void)ws_size;

    init_k<<<1, NT, 0, stream>>>(AgP);
    viterbi_fwd<<<NBLK, TPB, 0, stream>>>(unary, trans, bp, AgP);
    mbuild_k<<<NCH, NT, 0, stream>>>(bp, M);
    chase_k<<<1, NT, 0, stream>>>(AgP, trans, M, boundary, out);
    traceback_k<<<NCH, 64, 0, stream>>>(bp, boundary, out);
}